// Round 8
// baseline (1458.363 us; speedup 1.0000x reference)
//
#include <hip/hip_runtime.h>
#include <hip/hip_bf16.h>
#include <math.h>
#include <stdint.h>

#define D_   1024
#define H_   16
#define DK_  64
#define DV_  128
#define L_   3
#define FFN_ 4096
#define S_   1024
#define B_   4
#define NF_  6144   // fused QKVG output width

typedef __attribute__((ext_vector_type(8))) _Float16 f16x8;
typedef __attribute__((ext_vector_type(4))) _Float16 f16x4;
typedef __attribute__((ext_vector_type(4))) float f32x4;

__device__ __forceinline__ void gl2lds16(const void* g, void* l) {
    __builtin_amdgcn_global_load_lds(
        (const __attribute__((address_space(1))) void*)(uintptr_t)g,
        (__attribute__((address_space(3))) void*)(uintptr_t)l, 16, 0, 0);
}
#define MFMA16(a,b,c) __builtin_amdgcn_mfma_f32_16x16x32_f16(a,b,c,0,0,0)

// fast gelu (tanh-approx, sigmoid form): 0.5v(1+tanh(y)) == v*sigmoid(2y), hw v_exp
__device__ __forceinline__ float fast_gelu(float v) {
    float y = 1.5957691216f * (v + 0.044715f * v * v * v);
    return v * (1.0f / (1.0f + __expf(-y)));
}

// supertile swizzle: pid -> (m0, n0), 8x8 block groups for L2 locality.
// XCD-aware interior: m = wi&7 so pids equal mod 8 (same XCD) share the A panel.
__device__ __forceinline__ void tile_swizzle(int pid, int N, int* m0, int* n0) {
    int nb = N >> 7;
    int sgn = nb >> 3;
    int sid = pid >> 6, wi = pid & 63;
    int smi = sid / sgn, sni = sid - smi * sgn;
    *m0 = ((smi << 3) + (wi & 7)) << 7;
    *n0 = ((sni << 3) + (wi >> 3)) << 7;
}

// ---------------------------------------------------------------- embed (fp32 h)
__global__ __launch_bounds__(256) void k_embed(const int* __restrict__ tokens,
                                               const float* __restrict__ emb,
                                               float* __restrict__ h) {
    int i = blockIdx.x * 256 + threadIdx.x;
    int d  = i & (D_ - 1);
    int bs = i >> 10;
    int s  = bs & (S_ - 1);
    int b  = bs >> 10;
    int tok = (s == 0) ? 0 : tokens[b * S_ + s - 1];
    h[i] = emb[tok * D_ + d] * 32.0f;
}

// ---------------------------------------------------------------- layernorm -> fp16
__global__ __launch_bounds__(256) void k_ln(const float* __restrict__ x,
                                            const float* __restrict__ s,
                                            const float* __restrict__ b,
                                            _Float16* __restrict__ y) {
    int row = blockIdx.x;
    int t = threadIdx.x;
    size_t base = (size_t)row * D_ + t * 4;
    float4 xv = *(const float4*)&x[base];
    float sum = xv.x + xv.y + xv.z + xv.w;
    float ssq = xv.x * xv.x + xv.y * xv.y + xv.z * xv.z + xv.w * xv.w;
    __shared__ float sm1[4], sm2[4];
    #pragma unroll
    for (int off = 32; off > 0; off >>= 1) {
        sum += __shfl_down(sum, off, 64);
        ssq += __shfl_down(ssq, off, 64);
    }
    int lane = t & 63, w = t >> 6;
    if (lane == 0) { sm1[w] = sum; sm2[w] = ssq; }
    __syncthreads();
    sum = sm1[0] + sm1[1] + sm1[2] + sm1[3];
    ssq = sm2[0] + sm2[1] + sm2[2] + sm2[3];
    float mean = sum * (1.0f / D_);
    float var  = ssq * (1.0f / D_) - mean * mean;
    float inv  = 1.0f / sqrtf(var + 1e-5f);
    float4 sv = *(const float4*)&s[t * 4];
    float4 bv = *(const float4*)&b[t * 4];
    f16x4 o;
    o.x = (_Float16)((xv.x - mean) * inv * sv.x + bv.x);
    o.y = (_Float16)((xv.y - mean) * inv * sv.y + bv.y);
    o.z = (_Float16)((xv.z - mean) * inv * sv.z + bv.z);
    o.w = (_Float16)((xv.w - mean) * inv * sv.w + bv.w);
    *(f16x4*)&y[base] = o;
}

// ---------------------------------------------------------------- fused QKVG weight cast: 4 segments in one launch
__global__ __launch_bounds__(256) void k_wcast4(const float* __restrict__ wq,
                                                const float* __restrict__ wk,
                                                const float* __restrict__ wv,
                                                const float* __restrict__ wg,
                                                _Float16* __restrict__ dst) {
    int bid = blockIdx.x;
    const float* src; _Float16* out; int N; int local;
    if (bid < 1024)      { src = wq; out = dst;                 N = 1024; local = bid; }
    else if (bid < 2048) { src = wk; out = dst + 1024 * 1024;   N = 1024; local = bid - 1024; }
    else if (bid < 4096) { src = wv; out = dst + 2*1024*1024;   N = 2048; local = bid - 2048; }
    else                 { src = wg; out = dst + 4*1024*1024;   N = 2048; local = bid - 4096; }
    int ntiles = N >> 5;
    int n0 = (local % ntiles) * 32, k0 = (local / ntiles) * 32;
    __shared__ float Ts[32][33];
    int t = threadIdx.x;
    #pragma unroll
    for (int c = 0; c < 4; c++) {
        int e = c * 256 + t; int kr = e >> 5, nc = e & 31;
        Ts[kr][nc] = src[(size_t)(k0 + kr) * N + n0 + nc];
    }
    __syncthreads();
    #pragma unroll
    for (int c = 0; c < 4; c++) {
        int e = c * 256 + t; int nr = e >> 5, kc = e & 31;
        out[(size_t)(n0 + nr) * 1024 + k0 + kc] = (_Float16)Ts[kc][nr];
    }
}

// ---------------------------------------------------------------- weight cast+transpose: fp32 [K][N] -> fp16 [N][K]
__global__ __launch_bounds__(256) void k_wcast(const float* __restrict__ in,
                                               _Float16* __restrict__ out,
                                               int K, int N) {
    __shared__ float Ts[32][33];
    int n0 = blockIdx.x * 32, k0 = blockIdx.y * 32;
    int t = threadIdx.x;
    #pragma unroll
    for (int c = 0; c < 4; c++) {
        int e = c * 256 + t; int kr = e >> 5, nc = e & 31;
        Ts[kr][nc] = in[(size_t)(k0 + kr) * N + n0 + nc];
    }
    __syncthreads();
    #pragma unroll
    for (int c = 0; c < 4; c++) {
        int e = c * 256 + t; int nr = e >> 5, kc = e & 31;
        out[(size_t)(n0 + nr) * K + k0 + kc] = (_Float16)Ts[kc][nr];
    }
}

// ---------------------------------------------------------------- MFMA GEMM (128x128 tile): C = A @ Bt^T, f16 out
// flags: 2=+bias, 4=gelu, 16=rope on cols<2048 (QKVG)
__global__ __launch_bounds__(256) void k_gemm_mfma(
    const _Float16* __restrict__ A, const _Float16* __restrict__ Bt,
    const float* __restrict__ bias, _Float16* __restrict__ Ch,
    int M, int N, int K, int flags)
{
    __shared__ __attribute__((aligned(16))) _Float16 As[128 * 32];
    __shared__ __attribute__((aligned(16))) _Float16 Bs[128 * 32];
    int t = threadIdx.x;
    int m0, n0;
    tile_swizzle(blockIdx.x, N, &m0, &n0);
    int w = t >> 6, lane = t & 63;
    int quad = lane >> 4, l16 = lane & 15;
    int wm = (w >> 1) * 64, wn = (w & 1) * 64;
    const f16x8* aptr[4]; const f16x8* bptr[4];
    #pragma unroll
    for (int i = 0; i < 4; i++) {
        int ra = wm + i * 16 + l16;
        aptr[i] = (const f16x8*)&As[ra * 32 + ((quad ^ ((ra >> 1) & 3)) * 8)];
        int rb = wn + i * 16 + l16;
        bptr[i] = (const f16x8*)&Bs[rb * 32 + ((quad ^ ((rb >> 1) & 3)) * 8)];
    }
    f32x4 acc[4][4] = {};
    for (int k0 = 0; k0 < K; k0 += 32) {
        __syncthreads();
        #pragma unroll
        for (int c = 0; c < 2; c++) {
            int chunk = c * 256 + t;
            int row = chunk >> 2, cg = chunk & 3;
            int ko = (cg ^ ((row >> 1) & 3)) * 8;
            gl2lds16(A  + (size_t)(m0 + row) * K + k0 + ko, As + chunk * 8);
            gl2lds16(Bt + (size_t)(n0 + row) * K + k0 + ko, Bs + chunk * 8);
        }
        __syncthreads();
        f16x8 af[4], bfr[4];
        #pragma unroll
        for (int i = 0; i < 4; i++) af[i] = *aptr[i];
        #pragma unroll
        for (int j = 0; j < 4; j++) bfr[j] = *bptr[j];
        #pragma unroll
        for (int i = 0; i < 4; i++)
            #pragma unroll
            for (int j = 0; j < 4; j++)
                acc[i][j] = MFMA16(af[i], bfr[j], acc[i][j]);
    }
    #pragma unroll
    for (int i = 0; i < 4; i++) {
        #pragma unroll
        for (int r = 0; r < 4; r++) {
            int row = m0 + wm + i * 16 + quad * 4 + r;
            #pragma unroll
            for (int j = 0; j < 4; j++) {
                int col = n0 + wn + j * 16 + l16;
                float v = acc[i][j][r];
                if (flags & 2) v += bias[col];
                if (flags & 4) v = fast_gelu(v);
                if (flags & 16) {
                    if (col < 2048) {               // uniform across wave (16-col groups)
                        int p = (col & 63) >> 1;
                        int srow = row & (S_ - 1);
                        float ang = __expf(-(float)p * (1.0f / 31.0f) * 9.210340372f);
                        float ph = (float)srow * ang;
                        float sn, cs;
                        __sincosf(ph, &sn, &cs);
                        float partner = __shfl_xor(v, 1, 64);
                        v = (l16 & 1) ? (v * cs + partner * sn)
                                      : (v * cs - partner * sn);
                        if (col >= 1024) v *= 0.125f;   // DK^-0.5 for k
                    }
                }
                Ch[(size_t)row * N + col] = (_Float16)v;
            }
        }
    }
}

// ---------------------------------------------------------------- direct RMW GEMM (64x128 tile): Cf += A @ Bt^T (+bias)
// 1D grid of (M/64)*(N/128). XCD-aware decode: m = pid&63 so the 8 n-tiles
// sharing one A panel have pids equal mod 8 -> same XCD L2.
__global__ __launch_bounds__(256) void k_gemm_rmw(
    const _Float16* __restrict__ A, const _Float16* __restrict__ Bt,
    const float* __restrict__ bias, float* __restrict__ Cf,
    int M, int N, int K)
{
    __shared__ __attribute__((aligned(16))) _Float16 As[64 * 32];
    __shared__ __attribute__((aligned(16))) _Float16 Bs[128 * 32];
    int t = threadIdx.x;
    int pid = blockIdx.x;
    int m0 = (pid & 63) * 64;
    int n0 = (pid >> 6) * 128;
    int w = t >> 6, lane = t & 63;
    int quad = lane >> 4, l16 = lane & 15;
    int wm = (w >> 1) * 32, wn = (w & 1) * 64;
    const f16x8* aptr[2]; const f16x8* bptr[4];
    #pragma unroll
    for (int i = 0; i < 2; i++) {
        int ra = wm + i * 16 + l16;
        aptr[i] = (const f16x8*)&As[ra * 32 + ((quad ^ ((ra >> 1) & 3)) * 8)];
    }
    #pragma unroll
    for (int j = 0; j < 4; j++) {
        int rb = wn + j * 16 + l16;
        bptr[j] = (const f16x8*)&Bs[rb * 32 + ((quad ^ ((rb >> 1) & 3)) * 8)];
    }
    f32x4 acc[2][4] = {};
    for (int k0 = 0; k0 < K; k0 += 32) {
        __syncthreads();
        {   // A: 64x32 = 256 chunks (1/thread)
            int row = t >> 2, cg = t & 3;
            int ko = (cg ^ ((row >> 1) & 3)) * 8;
            gl2lds16(A + (size_t)(m0 + row) * K + k0 + ko, As + t * 8);
        }
        #pragma unroll
        for (int c = 0; c < 2; c++) {  // B: 128x32 = 512 chunks (2/thread)
            int chunk = c * 256 + t;
            int row = chunk >> 2, cg = chunk & 3;
            int ko = (cg ^ ((row >> 1) & 3)) * 8;
            gl2lds16(Bt + (size_t)(n0 + row) * K + k0 + ko, Bs + chunk * 8);
        }
        __syncthreads();
        f16x8 af[2], bfr[4];
        #pragma unroll
        for (int i = 0; i < 2; i++) af[i] = *aptr[i];
        #pragma unroll
        for (int j = 0; j < 4; j++) bfr[j] = *bptr[j];
        #pragma unroll
        for (int i = 0; i < 2; i++)
            #pragma unroll
            for (int j = 0; j < 4; j++)
                acc[i][j] = MFMA16(af[i], bfr[j], acc[i][j]);
    }
    #pragma unroll
    for (int i = 0; i < 2; i++) {
        #pragma unroll
        for (int r = 0; r < 4; r++) {
            int row = m0 + wm + i * 16 + quad * 4 + r;
            #pragma unroll
            for (int j = 0; j < 4; j++) {
                int col = n0 + wn + j * 16 + l16;
                float v = acc[i][j][r];
                if (bias) v += bias[col];
                size_t idx = (size_t)row * N + col;
                Cf[idx] += v;
            }
        }
    }
}

// ---------------------------------------------------------------- V transpose: fused[.,2048+h*128+dv] -> [B][H][128][S]
__global__ __launch_bounds__(256) void k_vtrans(const _Float16* __restrict__ vb,
                                                _Float16* __restrict__ Vt) {
    int st = blockIdx.x, dt = blockIdx.y, bh = blockIdx.z;
    int hh = bh & 15, b = bh >> 4;
    __shared__ __attribute__((aligned(16))) _Float16 Ts[64][72];
    int t = threadIdx.x;
    const _Float16* src = vb + (size_t)(b * S_ + st * 64) * NF_ + 2048 + hh * DV_ + dt * 64;
    #pragma unroll
    for (int c = 0; c < 2; c++) {
        int chunk = c * 256 + t;
        int r = chunk >> 3, co = (chunk & 7) * 8;
        *(f16x8*)&Ts[r][co] = *(const f16x8*)(src + (size_t)r * NF_ + co);
    }
    __syncthreads();
    _Float16* dst = Vt + ((size_t)bh * DV_ + dt * 64) * S_ + st * 64;
    #pragma unroll
    for (int c = 0; c < 2; c++) {
        int chunk = c * 256 + t;
        int dr = chunk >> 3, so = (chunk & 7) * 8;
        f16x8 val;
        #pragma unroll
        for (int j = 0; j < 8; j++) val[j] = Ts[so + j][dr];
        *(f16x8*)(dst + (size_t)dr * S_ + so) = val;
    }
}

// ---------------------------------------------------------------- MFMA retention attention + fused RMS/silu-gate epilogue
__global__ __launch_bounds__(256) void k_attn(const _Float16* __restrict__ qkvg,
                                              const _Float16* __restrict__ Vt,
                                              _Float16* __restrict__ oh) {
    int nt = blockIdx.x, bh = blockIdx.y;
    int hh = bh & 15, b = bh >> 4;
    int t = threadIdx.x, w = t >> 6, lane = t & 63;
    int quad = lane >> 4, l16 = lane & 15;
    int n0 = nt * 64;

    __shared__ __attribute__((aligned(16))) _Float16 Qs[64 * 64];
    __shared__ __attribute__((aligned(16))) _Float16 Ks[64 * 64];
    __shared__ __attribute__((aligned(16))) _Float16 Vs[128 * 64];
    __shared__ __attribute__((aligned(16))) _Float16 Ss[64 * 64];

    const _Float16* qg = qkvg + (size_t)(b * S_ + n0) * NF_ + hh * DK_;
    const _Float16* kg = qkvg + (size_t)(b * S_) * NF_ + 1024 + hh * DK_;
    const _Float16* vg = Vt + (size_t)bh * DV_ * S_;

    #pragma unroll
    for (int c = 0; c < 2; c++) {
        int chunk = c * 256 + t;
        int r = chunk >> 3, cg = chunk & 7;
        int ko = (cg ^ (r & 7)) * 8;
        gl2lds16(qg + (size_t)r * NF_ + ko, Qs + chunk * 8);
    }
    double gd   = 1.0 - exp2((double)(-5 - hh));
    double l2gd = log2(gd);
    float  l2g  = (float)l2gd;
    float rn[4];
    #pragma unroll
    for (int r = 0; r < 4; r++) {
        int n = n0 + w * 16 + quad * 4 + r;
        double rowsum = (1.0 - exp2(l2gd * (double)(n + 1))) / (1.0 - gd);
        rn[r] = (float)(1.0 / sqrt(rowsum));
    }
    int ra = w * 16 + l16;
    const f16x8* qp0 = (const f16x8*)&Qs[ra * 64 + (( quad      ^ (ra & 7)) * 8)];
    const f16x8* qp1 = (const f16x8*)&Qs[ra * 64 + (((quad + 4) ^ (ra & 7)) * 8)];
    const f16x8* sp0 = (const f16x8*)&Ss[ra * 64 + (( quad      ^ (ra & 7)) * 8)];
    const f16x8* sp1 = (const f16x8*)&Ss[ra * 64 + (((quad + 4) ^ (ra & 7)) * 8)];
    const f16x8* kp0[4]; const f16x8* kp1[4];
    const f16x8* vp0[8]; const f16x8* vp1[8];
    #pragma unroll
    for (int j = 0; j < 4; j++) {
        int rb = j * 16 + l16;
        kp0[j] = (const f16x8*)&Ks[rb * 64 + (( quad      ^ (rb & 7)) * 8)];
        kp1[j] = (const f16x8*)&Ks[rb * 64 + (((quad + 4) ^ (rb & 7)) * 8)];
    }
    #pragma unroll
    for (int j = 0; j < 8; j++) {
        int rv = j * 16 + l16;
        vp0[j] = (const f16x8*)&Vs[rv * 64 + (( quad      ^ (rv & 7)) * 8)];
        vp1[j] = (const f16x8*)&Vs[rv * 64 + (((quad + 4) ^ (rv & 7)) * 8)];
    }
    f32x4 oacc[8] = {};
    float absAcc[4] = {};

    for (int mt = 0; mt <= nt; mt++) {
        int m0 = mt * 64;
        __syncthreads();
        #pragma unroll
        for (int c = 0; c < 2; c++) {
            int chunk = c * 256 + t;
            int r = chunk >> 3, cg = chunk & 7;
            int ko = (cg ^ (r & 7)) * 8;
            gl2lds16(kg + (size_t)(m0 + r) * NF_ + ko, Ks + chunk * 8);
        }
        #pragma unroll
        for (int c = 0; c < 4; c++) {
            int chunk = c * 256 + t;
            int r = chunk >> 3, cg = chunk & 7;
            int ko = (cg ^ (r & 7)) * 8;
            gl2lds16(vg + (size_t)r * S_ + m0 + ko, Vs + chunk * 8);
        }
        __syncthreads();
        f16x8 a0 = *qp0, a1 = *qp1;
        f32x4 sacc[4] = {};
        #pragma unroll
        for (int j = 0; j < 4; j++) {
            sacc[j] = MFMA16(a0, *kp0[j], sacc[j]);
            sacc[j] = MFMA16(a1, *kp1[j], sacc[j]);
        }
        #pragma unroll
        for (int j = 0; j < 4; j++) {
            int m = m0 + j * 16 + l16;
            #pragma unroll
            for (int r = 0; r < 4; r++) {
                int n = n0 + w * 16 + quad * 4 + r;
                float dm = (n >= m) ? exp2f((float)(n - m) * l2g) * rn[r] : 0.0f;
                float sv = sacc[j][r] * dm;
                absAcc[r] += fabsf(sv);
                int rowS = w * 16 + quad * 4 + r;
                int colS = j * 16 + l16;
                Ss[rowS * 64 + ((((colS >> 3) ^ (rowS & 7)) << 3) | (colS & 7))] = (_Float16)sv;
            }
        }
        __syncthreads();
        f16x8 s0 = *sp0, s1 = *sp1;
        #pragma unroll
        for (int j = 0; j < 8; j++) {
            oacc[j] = MFMA16(s0, *vp0[j], oacc[j]);
            oacc[j] = MFMA16(s1, *vp1[j], oacc[j]);
        }
    }
    // |S| row sums across the 16 col-lanes
    #pragma unroll
    for (int r = 0; r < 4; r++) {
        float s_ = absAcc[r];
        #pragma unroll
        for (int off = 1; off < 16; off <<= 1) s_ += __shfl_xor(s_, off, 64);
        absAcc[r] = s_;
    }
    // fused epilogue: qk-normalize, RMS over 128, silu(g)-gate, f16 store
    #pragma unroll
    for (int r = 0; r < 4; r++) {
        int n = n0 + w * 16 + quad * 4 + r;
        float sc = 1.0f / fmaxf(absAcc[r], 1.0f);
        float vals[8];
        float ssq = 0.0f;
        #pragma unroll
        for (int j = 0; j < 8; j++) {
            vals[j] = oacc[j][r] * sc;
            ssq += vals[j] * vals[j];
        }
        #pragma unroll
        for (int off = 1; off < 16; off <<= 1) ssq += __shfl_xor(ssq, off, 64);
        float rms = 1.0f / sqrtf(ssq * (1.0f / 128.0f) + 1e-6f);
        const _Float16* gg = qkvg + (size_t)(b * S_ + n) * NF_ + 4096 + hh * DV_;
        _Float16* og = oh + (size_t)(b * S_ + n) * (H_ * DV_) + hh * DV_;
        #pragma unroll
        for (int j = 0; j < 8; j++) {
            float gv = (float)gg[j * 16 + l16];
            float sig = 1.0f / (1.0f + __expf(-gv));
            og[j * 16 + l16] = (_Float16)(gv * sig * vals[j] * rms);
        }
    }
}

// ---------------------------------------------------------------- final LN + logits (V=2) + log_softmax
__global__ __launch_bounds__(256) void k_final(const float* __restrict__ x,
                                               const float* __restrict__ s,
                                               const float* __restrict__ b,
                                               const float* __restrict__ Wout,
                                               float* __restrict__ out) {
    int row = blockIdx.x;
    int t = threadIdx.x;
    size_t base = (size_t)row * D_ + t * 4;
    float4 xv = *(const float4*)&x[base];
    float sum = xv.x + xv.y + xv.z + xv.w;
    float ssq = xv.x * xv.x + xv.y * xv.y + xv.z * xv.z + xv.w * xv.w;
    __shared__ float sm1[4], sm2[4];
    #pragma unroll
    for (int off = 32; off > 0; off >>= 1) {
        sum += __shfl_down(sum, off, 64);
        ssq += __shfl_down(ssq, off, 64);
    }
    int lane = t & 63, w = t >> 6;
    if (lane == 0) { sm1[w] = sum; sm2[w] = ssq; }
    __syncthreads();
    sum = sm1[0] + sm1[1] + sm1[2] + sm1[3];
    ssq = sm2[0] + sm2[1] + sm2[2] + sm2[3];
    float mean = sum * (1.0f / D_);
    float var  = ssq * (1.0f / D_) - mean * mean;
    float inv  = 1.0f / sqrtf(var + 1e-5f);
    float4 sv = *(const float4*)&s[t * 4];
    float4 bv = *(const float4*)&b[t * 4];
    float ln[4];
    ln[0] = (xv.x - mean) * inv * sv.x + bv.x;
    ln[1] = (xv.y - mean) * inv * sv.y + bv.y;
    ln[2] = (xv.z - mean) * inv * sv.z + bv.z;
    ln[3] = (xv.w - mean) * inv * sv.w + bv.w;
    float l0 = 0.0f, l1 = 0.0f;
    #pragma unroll
    for (int i = 0; i < 4; i++) {
        int d = t * 4 + i;
        l0 += ln[i] * Wout[d * 2 + 0];
        l1 += ln[i] * Wout[d * 2 + 1];
    }
    #pragma unroll
    for (int off = 32; off > 0; off >>= 1) {
        l0 += __shfl_down(l0, off, 64);
        l1 += __shfl_down(l1, off, 64);
    }
    __syncthreads();
    if (lane == 0) { sm1[w] = l0; sm2[w] = l1; }
    __syncthreads();
    if (t == 0) {
        l0 = sm1[0] + sm1[1] + sm1[2] + sm1[3];
        l1 = sm2[0] + sm2[1] + sm2[2] + sm2[3];
        float mx  = fmaxf(l0, l1);
        float lse = mx + logf(expf(l0 - mx) + expf(l1 - mx));
        out[(size_t)row * 2 + 0] = l0 - lse;
        out[(size_t)row * 2 + 1] = l1 - lse;
    }
}

// ---------------------------------------------------------------- launch
extern "C" void kernel_launch(void* const* d_in, const int* in_sizes, int n_in,
                              void* d_out, int out_size, void* d_ws, size_t ws_size,
                              hipStream_t stream) {
    const int*   tokens = (const int*)d_in[0];
    const float* emb    = (const float*)d_in[1];
    const float* Wq     = (const float*)d_in[2];
    const float* Wk     = (const float*)d_in[3];
    const float* Wv     = (const float*)d_in[4];
    const float* Wg     = (const float*)d_in[5];
    const float* Wo     = (const float*)d_in[6];
    const float* ln1_s  = (const float*)d_in[7];
    const float* ln1_b  = (const float*)d_in[8];
    const float* ln2_s  = (const float*)d_in[9];
    const float* ln2_b  = (const float*)d_in[10];
    const float* W1     = (const float*)d_in[11];
    const float* b1     = (const float*)d_in[12];
    const float* W2     = (const float*)d_in[13];
    const float* b2     = (const float*)d_in[14];
    const float* lnf_s  = (const float*)d_in[15];
    const float* lnf_b  = (const float*)d_in[16];
    const float* Wout   = (const float*)d_in[17];

    float* ws = (float*)d_ws;
    const size_t M1 = 1u << 20;
    // layout in float units (total 35M floats = 140 MB):
    float*     h    = ws;                              // [0,4M) fp32
    _Float16*  x1h  = (_Float16*)(ws + 4 * M1);        // [4M,6M) f16 [4096][1024]
    _Float16*  whb  = (_Float16*)(ws + 6 * M1);        // [6M,14M) f16 weights
    _Float16*  wQKVG= whb;                             // [6144][1024]
    _Float16*  woT  = whb + 6 * M1;                    // [1024][2048]
    _Float16*  w1T  = whb + 8 * M1;                    // [4096][1024]
    _Float16*  w2T  = whb + 12 * M1;                   // [1024][4096]
    _Float16*  qkvg = (_Float16*)(ws + 14 * M1);       // [14M,27M) f16 [4096][6144]
    _Float16*  Vth  = (_Float16*)(ws + 27 * M1);       // [27M,31M) f16 [64][128][1024]
    _Float16*  oh   = (_Float16*)(ws + 31 * M1);       // [31M,35M) f16 [4096][2048]
    _Float16*  f1h  = (_Float16*)(ws + 14 * M1);       // overlays qkvg (dead after attn)

    k_embed<<<16384, 256, 0, stream>>>(tokens, emb, h);

    for (int l = 0; l < L_; l++) {
        const float* pWq = Wq + (size_t)l * M1;
        const float* pWk = Wk + (size_t)l * M1;
        const float* pWv = Wv + (size_t)l * 2 * M1;
        const float* pWg = Wg + (size_t)l * 2 * M1;
        const float* pWo = Wo + (size_t)l * 2 * M1;
        const float* pW1 = W1 + (size_t)l * 4 * M1;
        const float* pW2 = W2 + (size_t)l * 4 * M1;

        k_wcast4<<<6144, 256, 0, stream>>>(pWq, pWk, pWv, pWg, wQKVG);
        k_wcast<<<dim3(32, 64),  256, 0, stream>>>(pWo, woT, 2048, 1024);
        k_wcast<<<dim3(128, 32), 256, 0, stream>>>(pW1, w1T, 1024, 4096);
        k_wcast<<<dim3(32, 128), 256, 0, stream>>>(pW2, w2T, 4096, 1024);

        k_ln<<<4096, 256, 0, stream>>>(h, ln1_s + l * D_, ln1_b + l * D_, x1h);
        // fused QKVG (rope fused in epilogue): [4096][6144] = x1h @ wQKVG^T
        k_gemm_mfma<<<dim3(1536), 256, 0, stream>>>(x1h, wQKVG, nullptr, qkvg,
                                                    4096, NF_, 1024, 16);
        k_vtrans<<<dim3(16, 2, 64), 256, 0, stream>>>(qkvg, Vth);
        k_attn<<<dim3(16, 64), 256, 0, stream>>>(qkvg, Vth, oh);
        // h += oh @ Wo  (direct RMW, XCD-aware 1D grid 512)
        k_gemm_rmw<<<dim3(512), 256, 0, stream>>>(oh, woT, nullptr, h,
                                                  4096, 1024, 2048);
        k_ln<<<4096, 256, 0, stream>>>(h, ln2_s + l * D_, ln2_b + l * D_, x1h);
        k_gemm_mfma<<<dim3(1024), 256, 0, stream>>>(x1h, w1T, b1 + l * FFN_, f1h,
                                                    4096, 4096, 1024, 2 | 4);
        // h += f1h @ W2 + b2  (direct RMW)
        k_gemm_rmw<<<dim3(512), 256, 0, stream>>>(f1h, w2T, b2 + l * D_, h,
                                                  4096, 1024, 4096);
    }
    k_final<<<4096, 256, 0, stream>>>(h, lnf_s, lnf_b, Wout, (float*)d_out);
}